// Round 5
// baseline (557.239 us; speedup 1.0000x reference)
//
#include <hip/hip_runtime.h>
#include <cstdint>
#include <cstddef>

#define N_ROWS 131072   // B*T
#define T_LEN 2048
#define B_BATCH 64
#define H_DIM 128
#define GEMM_GRID 1024
#define GEMM_ROWS 128   // rows per gemm block
#define GWND 8          // gemm staging window
#define WND 16          // rnn window (prefetch depth)
#define LOG2E 1.4426950408889634f

typedef _Float16 half2_t __attribute__((ext_vector_type(2)));
typedef _Float16 half4_t __attribute__((ext_vector_type(4)));

// DPP cross-lane ops (VALU pipe, no LDS):
// quad_perm(1,0,3,2)=0xB1 (xor1), quad_perm(2,3,0,1)=0x4E (xor2),
// ROW_HALF_MIRROR=0x141 (l <-> l^7 within each 8-lane group).
__device__ __forceinline__ float dpp_xor1(float x) {
  int i = __float_as_int(x);
  return __int_as_float(__builtin_amdgcn_update_dpp(i, i, 0xB1, 0xF, 0xF, true));
}
__device__ __forceinline__ float dpp_xor2(float x) {
  int i = __float_as_int(x);
  return __int_as_float(__builtin_amdgcn_update_dpp(i, i, 0x4E, 0xF, 0xF, true));
}
__device__ __forceinline__ float dpp_mirror8(float x) {
  int i = __float_as_int(x);
  return __int_as_float(__builtin_amdgcn_update_dpp(i, i, 0x141, 0xF, 0xF, true));
}

__device__ __forceinline__ float sigmoid2_fast(float spp) {
  // y = 1/(1 + 2^spp), spp already scaled by -log2e
  return __builtin_amdgcn_rcpf(1.0f + __builtin_amdgcn_exp2f(spp));
}

// ---------------------------------------------------------------------------
// Kernel 1: Wx = x @ W^T + fused BN column stats, f16 inputs via v_dot2.
// Lane (hq = tid>>2, ks = tid&3) owns k-slice [32ks,32ks+32) of rows
// {h_own, h_alt}; parity-swapped row order -> select-free 2-stage DPP reduce.
// x rows staged as f16 (converted during staging), double-buffered.
// ---------------------------------------------------------------------------
__global__ __launch_bounds__(256) void gemm_bn_kernel(
    const float* __restrict__ x, const float* __restrict__ W,
    float* __restrict__ Wx, float* __restrict__ stats)
{
  const int tid = threadIdx.x;
  const int hq = tid >> 2;           // 0..63
  const int ks = tid & 3;            // 0..3
  const int k0 = ks << 5;            // 32-float k-slice base
  const int h_own = hq + ((ks & 1) << 6);
  const int h_alt = hq + (((ks & 1) ^ 1) << 6);

  half2_t Wh[2][16];
  {
    const float* w0 = W + (size_t)h_own * H_DIM + k0;
    const float* w1 = W + (size_t)h_alt * H_DIM + k0;
#pragma unroll
    for (int i = 0; i < 16; ++i) {
      half2_t a, b;
      a.x = (_Float16)w0[2 * i]; a.y = (_Float16)w0[2 * i + 1];
      b.x = (_Float16)w1[2 * i]; b.y = (_Float16)w1[2 * i + 1];
      Wh[0][i] = a; Wh[1][i] = b;
    }
  }

  __shared__ __align__(16) _Float16 xs[2][GWND][H_DIM];

  const int r0 = blockIdx.x * GEMM_ROWS;
  const int sr = tid >> 5;   // staging row 0..7
  const int c4 = tid & 31;   // staging float4 col

  {
    float4 v = *reinterpret_cast<const float4*>(&x[(size_t)(r0 + sr) * H_DIM + (c4 << 2)]);
    half4_t h; h.x = (_Float16)v.x; h.y = (_Float16)v.y; h.z = (_Float16)v.z; h.w = (_Float16)v.w;
    *reinterpret_cast<half4_t*>(&xs[0][sr][c4 << 2]) = h;
  }
  __syncthreads();

  float sum = 0.f, sq = 0.f;

  for (int wnd = 0; wnd < GEMM_ROWS; wnd += GWND) {
    const int bw = (wnd >> 3) & 1;
    const bool more = (wnd + GWND < GEMM_ROWS);
    float4 sv;
    if (more)
      sv = *reinterpret_cast<const float4*>(
          &x[(size_t)(r0 + wnd + GWND + sr) * H_DIM + (c4 << 2)]);

#pragma unroll
    for (int r = 0; r < GWND; ++r) {
      const uint4* xv = reinterpret_cast<const uint4*>(&xs[bw][r][k0]);
      uint4 q0 = xv[0], q1 = xv[1], q2 = xv[2], q3 = xv[3];
      half2_t xh[16];
      xh[0]  = __builtin_bit_cast(half2_t, q0.x);
      xh[1]  = __builtin_bit_cast(half2_t, q0.y);
      xh[2]  = __builtin_bit_cast(half2_t, q0.z);
      xh[3]  = __builtin_bit_cast(half2_t, q0.w);
      xh[4]  = __builtin_bit_cast(half2_t, q1.x);
      xh[5]  = __builtin_bit_cast(half2_t, q1.y);
      xh[6]  = __builtin_bit_cast(half2_t, q1.z);
      xh[7]  = __builtin_bit_cast(half2_t, q1.w);
      xh[8]  = __builtin_bit_cast(half2_t, q2.x);
      xh[9]  = __builtin_bit_cast(half2_t, q2.y);
      xh[10] = __builtin_bit_cast(half2_t, q2.z);
      xh[11] = __builtin_bit_cast(half2_t, q2.w);
      xh[12] = __builtin_bit_cast(half2_t, q3.x);
      xh[13] = __builtin_bit_cast(half2_t, q3.y);
      xh[14] = __builtin_bit_cast(half2_t, q3.z);
      xh[15] = __builtin_bit_cast(half2_t, q3.w);

      float p0 = 0.f, p1 = 0.f;
#pragma unroll
      for (int i = 0; i < 16; ++i) {
        p0 = __builtin_amdgcn_fdot2(xh[i], Wh[0][i], p0, false);
        p1 = __builtin_amdgcn_fdot2(xh[i], Wh[1][i], p1, false);
      }
      float q = p0 + dpp_xor1(p1);
      float s = q + dpp_xor2(q);
      if (ks < 2) {
        Wx[(size_t)(r0 + wnd + r) * H_DIM + h_own] = s;
        sum += s;
        sq = fmaf(s, s, sq);
      }
    }
    if (more) {
      half4_t h; h.x = (_Float16)sv.x; h.y = (_Float16)sv.y; h.z = (_Float16)sv.z; h.w = (_Float16)sv.w;
      *reinterpret_cast<half4_t*>(&xs[bw ^ 1][sr][c4 << 2]) = h;
    }
    __syncthreads();
  }
  if (ks < 2) {
    atomicAdd(&stats[h_own], sum);
    atomicAdd(&stats[H_DIM + h_own], sq);
  }
}

// ---------------------------------------------------------------------------
__global__ void bn_finalize_kernel(float* ws, const float* __restrict__ gamma,
                                   const float* __restrict__ beta)
{
  const int h = threadIdx.x;
  const float invN = 1.0f / (float)N_ROWS;
  float mean = ws[h] * invN;
  float e2   = ws[H_DIM + h] * invN;
  float var  = e2 - mean * mean;
  float scl  = gamma[h] * rsqrtf(var + 1e-5f);
  ws[2 * H_DIM + h] = scl;
  ws[3 * H_DIM + h] = beta[h] - mean * scl;
}

// ---------------------------------------------------------------------------
// Kernel 3: recurrence, in-place on d_out (holds Wx). One block/batch,
// 256 thr (4 waves). f16 y in LDS ping-pong; V as f16 pre-scaled by -log2e
// (exp2-domain sigmoid); per-lane: 4 rows x 16-k slice via v_dot2_f32_f16;
// select-free 3-stage DPP reduce-scatter (xor1, xor2, row_half_mirror).
// Lane l (within 8-group): accumulator j holds row j ^ g, g=(l&3)^(3*(l>>2&1)).
// WND=16 window: wx prefetched to regs, y flushed to global once per window.
// ---------------------------------------------------------------------------
__global__ __launch_bounds__(256) void rnn_kernel(
    const float* __restrict__ V, float* __restrict__ out,
    const float* __restrict__ ws)
{
  const int tid = threadIdx.x;
  const int hq = tid >> 3;           // 0..31
  const int l7 = tid & 7;            // lane within 8-group
  const int g  = (l7 & 3) ^ (3 * ((l7 >> 2) & 1));
  const int h_own = hq + (g << 5);
  const bool wr = (tid & 4) == 0;    // lanes l7<4: unique row owners/writers

  // V fragment: rows h_j = hq + 32*(j^g), k-slice [16*l7, 16*l7+16), as f16
  // pre-scaled by -log2e.
  half2_t Vh[4][8];
#pragma unroll
  for (int j = 0; j < 4; ++j) {
    const int hrow = hq + (((unsigned)(j ^ g)) << 5);
    const float* vp = V + (size_t)hrow * H_DIM + (l7 << 4);
#pragma unroll
    for (int i = 0; i < 8; ++i) {
      half2_t h;
      h.x = (_Float16)(-LOG2E * vp[2 * i]);
      h.y = (_Float16)(-LOG2E * vp[2 * i + 1]);
      Vh[j][i] = h;
    }
  }
  const float scl2 = ws[2 * H_DIM + h_own] * (-LOG2E);
  const float shf2 = ws[3 * H_DIM + h_own] * (-LOG2E);

  __shared__ __align__(16) _Float16 ylds[2][H_DIM];

  float* outb = out + (size_t)blockIdx.x * T_LEN * H_DIM;

  if (tid < H_DIM) { ylds[0][tid] = (_Float16)0.f; ylds[1][tid] = (_Float16)0.f; }

  float wxp[WND];
  if (wr) {
#pragma unroll
    for (int u = 0; u < WND; ++u)
      wxp[u] = fmaf(outb[(size_t)u * H_DIM + h_own], scl2, shf2);
  } else {
#pragma unroll
    for (int u = 0; u < WND; ++u) wxp[u] = 0.f;
  }
  __syncthreads();

  float yreg[WND];

  for (int w = 0; w < T_LEN; w += WND) {
    const bool more = (w + WND < T_LEN);
    float wxn[WND];
    if (more && wr) {  // prefetch next window's wx (hides under 16 steps)
#pragma unroll
      for (int u = 0; u < WND; ++u)
        wxn[u] = outb[(size_t)(w + WND + u) * H_DIM + h_own];
    } else {
#pragma unroll
      for (int u = 0; u < WND; ++u) wxn[u] = 0.f;
    }

#pragma unroll
    for (int u = 0; u < WND; ++u) {
      const int t = w + u;
      // read own 16-half slice of y (2 x ds_read_b128, mostly broadcast)
      const uint4* yv = reinterpret_cast<const uint4*>(&ylds[t & 1][l7 << 4]);
      uint4 w0 = yv[0], w1 = yv[1];
      half2_t y2[8];
      y2[0] = __builtin_bit_cast(half2_t, w0.x);
      y2[1] = __builtin_bit_cast(half2_t, w0.y);
      y2[2] = __builtin_bit_cast(half2_t, w0.z);
      y2[3] = __builtin_bit_cast(half2_t, w0.w);
      y2[4] = __builtin_bit_cast(half2_t, w1.x);
      y2[5] = __builtin_bit_cast(half2_t, w1.y);
      y2[6] = __builtin_bit_cast(half2_t, w1.z);
      y2[7] = __builtin_bit_cast(half2_t, w1.w);

      float a0 = 0.f, a1 = 0.f, a2 = 0.f, a3 = 0.f;
#pragma unroll
      for (int i = 0; i < 8; ++i) {
        a0 = __builtin_amdgcn_fdot2(y2[i], Vh[0][i], a0, false);
        a1 = __builtin_amdgcn_fdot2(y2[i], Vh[1][i], a1, false);
        a2 = __builtin_amdgcn_fdot2(y2[i], Vh[2][i], a2, false);
        a3 = __builtin_amdgcn_fdot2(y2[i], Vh[3][i], a3, false);
      }
      // select-free reduce-scatter: lane ends with full dot of row h_own
      float b0 = a0 + dpp_xor1(a1);
      float b1 = a2 + dpp_xor1(a3);
      float c  = b0 + dpp_xor2(b1);
      float red = c + dpp_mirror8(c);
      const float spp = red + wxp[u];
      const float y = sigmoid2_fast(spp);
      if (wr) ylds[(t & 1) ^ 1][h_own] = (_Float16)y;
      yreg[u] = y;
      // LDS visibility only; global loads/stores stay in flight.
      asm volatile("s_waitcnt lgkmcnt(0)\n\ts_barrier" ::: "memory");
    }

    if (wr) {  // flush window outputs (overwrites consumed Wx)
#pragma unroll
      for (int u = 0; u < WND; ++u)
        outb[(size_t)(w + u) * H_DIM + h_own] = yreg[u];
    }
#pragma unroll
    for (int u = 0; u < WND; ++u) wxp[u] = fmaf(wxn[u], scl2, shf2);
  }
}

// ---------------------------------------------------------------------------
extern "C" void kernel_launch(void* const* d_in, const int* in_sizes, int n_in,
                              void* d_out, int out_size, void* d_ws, size_t ws_size,
                              hipStream_t stream)
{
  (void)in_sizes; (void)n_in; (void)out_size; (void)ws_size;
  const float* x     = (const float*)d_in[0];
  const float* W     = (const float*)d_in[1];
  const float* V     = (const float*)d_in[2];
  const float* gamma = (const float*)d_in[3];
  const float* beta  = (const float*)d_in[4];
  float* out = (float*)d_out;
  float* ws  = (float*)d_ws;

  hipMemsetAsync(ws, 0, 2 * H_DIM * sizeof(float), stream);
  gemm_bn_kernel<<<GEMM_GRID, 256, 0, stream>>>(x, W, out, ws);
  bn_finalize_kernel<<<1, H_DIM, 0, stream>>>(ws, gamma, beta);
  rnn_kernel<<<B_BATCH, 256, 0, stream>>>(V, out, ws);
}